// Round 12
// baseline (296.912 us; speedup 1.0000x reference)
//
#include <hip/hip_runtime.h>

typedef __attribute__((ext_vector_type(8))) short bf16x8;
typedef __attribute__((ext_vector_type(4))) float f32x4;
typedef __attribute__((ext_vector_type(8))) unsigned short u16x8;
typedef unsigned long long u64t;
typedef unsigned int u32t;

#define NROWS 65536
#define DDIM  256
#define KCODE 2048

__device__ __forceinline__ unsigned short f2bf_rne(float f) {
  unsigned int u = __builtin_bit_cast(unsigned int, f);
  unsigned int r = (u + 0x7fffu + ((u >> 16) & 1u)) >> 16;
  return (unsigned short)r;
}
__device__ __forceinline__ float bf2f(unsigned short h) {
  unsigned int u = ((unsigned int)h) << 16;
  return __builtin_bit_cast(float, u);
}

typedef const unsigned int __attribute__((address_space(1)))* gp1_t;
typedef unsigned int __attribute__((address_space(3)))* lp3_t;
__device__ __forceinline__ void gload_lds16(const void* g, void* l) {
  __builtin_amdgcn_global_load_lds((gp1_t)g, (lp3_t)l, 16, 0, 0);
}

__device__ __forceinline__ u64t shfl_xor_u64(u64t v, int off) {
  u32t lo = (u32t)v, hi = (u32t)(v >> 32);
  lo = __shfl_xor(lo, off);
  hi = __shfl_xor(hi, off);
  return ((u64t)hi << 32) | lo;
}

// --- prep A: x -> [hi(256)|lo(256)] bf16 per row (overlay on d_out) + ||x||^2 + key init ---
__global__ __launch_bounds__(256) void prep_A(const float* __restrict__ x,
                                              unsigned short* __restrict__ Ap,
                                              float* __restrict__ frow,
                                              u64t* __restrict__ keyArr) {
  const int t   = threadIdx.x;
  const int row = blockIdx.x * 8 + (t >> 5);
  const int d0  = (t & 31) * 8;
  const float* xr = x + (size_t)row * DDIM + d0;
  float4 v0 = *reinterpret_cast<const float4*>(xr);
  float4 v1 = *reinterpret_cast<const float4*>(xr + 4);
  float vv[8] = {v0.x, v0.y, v0.z, v0.w, v1.x, v1.y, v1.z, v1.w};
  u16x8 hi, lo;
  float ss = 0.f;
  #pragma unroll
  for (int i = 0; i < 8; ++i) {
    ss += vv[i] * vv[i];
    unsigned short h = f2bf_rne(vv[i]);
    hi[i] = h;
    lo[i] = f2bf_rne(vv[i] - bf2f(h));
  }
  char* rowp = (char*)Ap + (size_t)row * 1024;
  *reinterpret_cast<u16x8*>(rowp + d0 * 2)       = hi;
  *reinterpret_cast<u16x8*>(rowp + 512 + d0 * 2) = lo;
  #pragma unroll
  for (int off = 16; off; off >>= 1) ss += __shfl_xor(ss, off);
  if ((t & 31) == 0) { frow[row] = ss; keyArr[row] = ~0ull; }
}

// --- prep B: E[d][k] -> Bp[k][1024B]=[hi 512|lo 512] bf16 k-major; enorm; Etg[k][d] fp32 ---
__global__ __launch_bounds__(256) void prep_B(const float* __restrict__ E,
                                              unsigned short* __restrict__ Bp,
                                              float* __restrict__ enorm,
                                              float* __restrict__ Etg) {
  const int k0 = blockIdx.x;
  const int d  = threadIdx.x;
  float v = E[(size_t)d * KCODE + k0];
  Etg[(size_t)k0 * DDIM + d] = v;
  unsigned short h = f2bf_rne(v);
  unsigned short l = f2bf_rne(v - bf2f(h));
  unsigned short* col = Bp + (size_t)k0 * 512;
  col[d] = h; col[256 + d] = l;
  float s = v * v;
  #pragma unroll
  for (int off = 32; off; off >>= 1) s += __shfl_xor(s, off);
  __shared__ float wsum[4];
  if ((threadIdx.x & 63) == 0) wsum[threadIdx.x >> 6] = s;
  __syncthreads();
  if (threadIdx.x == 0) enorm[k0] = (wsum[0] + wsum[1]) + (wsum[2] + wsum[3]);
}

// --- main: PERSISTENT blocks, barrier-free K-loop.
// 256 blocks (1/CU). Block b: cb = b>>4 (128 codes, FILLED ONCE into 128KB
// LDS: 8 chunks x {ch 8K | cl 8K}); then 16 x-slabs of 256 rows, x fragments
// per-lane in registers. After the single fill barrier the LDS is read-only:
// ZERO barriers, zero staging, zero manual vmcnt in the entire compute loop.
// Waves free-run -> ds_read/VALU/x-loads of one wave overlap MFMA of others.
__global__ __launch_bounds__(512, 2) void vq_nn(
    const unsigned short* __restrict__ Ap,   // x packed  [row][hi|lo] 1024 B/row
    const unsigned short* __restrict__ Bp,   // codes     [k][hi|lo]   1024 B/code
    const float* __restrict__ enorm,
    const float* __restrict__ frow,
    u64t* __restrict__ keyArr)
{
  extern __shared__ __align__(16) char lds[];   // 8 chunks x 16KB = 128 KB

  const int tid = threadIdx.x;
  const int w   = tid >> 6;
  const int l   = tid & 63;
  const int l15 = l & 15;
  const int lg  = l >> 4;
  const int wr  = w >> 2;      // code half (0..1): 64 codes
  const int wc  = w & 3;       // x quarter (0..3): 64 cols

  const int cb = blockIdx.x >> 4;    // 0..15: 128-code slab (filled once)
  const int g  = blockIdx.x & 15;    // 16 x-slabs: nb = g*16 + i

  const char* BpB = (const char*)Bp + (size_t)cb * 128 * 1024;

  // ---- one-shot code fill: 16 gloads/thread, pre-swizzled source ----
  {
    const int kf   = tid >> 2;                 // code row 0..127
    const int slot = (tid & 3) * 16;
    const int srcS = slot ^ (((kf >> 1) & 3) << 4);
    const char* srcR = BpB + (size_t)kf * 1024 + srcS;
    char* dstB = lds + w * 1024;               // wave-uniform base (+lane*16 by HW)
    #pragma unroll
    for (int c = 0; c < 8; ++c) {
      gload_lds16(srcR + c * 64,        dstB + c * 16384);          // ch
      gload_lds16(srcR + c * 64 + 512,  dstB + c * 16384 + 8192);   // cl
    }
  }
  __syncthreads();   // compiler emits vmcnt(0)+lgkmcnt(0) drain; ONLY barrier

  // LDS read addressing (XOR pair matches fill swizzle; r9-verified, 0 conflicts)
  const int koX = (lg * 16) ^ ((l15 & 6) << 3);
  int aOff[4];
  #pragma unroll
  for (int fr = 0; fr < 4; ++fr) aOff[fr] = (wr * 64 + fr * 16 + l15) * 64;

#define MM16(av, bv)                                                          \
  __builtin_amdgcn_s_setprio(1);                                              \
  _Pragma("unroll")                                                           \
  for (int i_ = 0; i_ < 4; ++i_)                                              \
    _Pragma("unroll")                                                         \
    for (int j_ = 0; j_ < 4; ++j_)                                            \
      acc[i_][j_] = __builtin_amdgcn_mfma_f32_16x16x32_bf16(                  \
          (av)[i_], (bv)[j_], acc[i_][j_], 0, 0, 0);                          \
  __builtin_amdgcn_s_setprio(0);

  for (int i = 0; i < 16; ++i) {
    const int nb = g * 16 + i;
    const char* ApB = (const char*)Ap + (size_t)nb * 256 * 1024;

    const char* xp[4];
    float fcol[4];
    #pragma unroll
    for (int fc = 0; fc < 4; ++fc) {
      const int col = wc * 64 + fc * 16 + l15;
      xp[fc]   = ApB + (size_t)col * 1024 + lg * 16;
      fcol[fc] = frow[nb * 256 + col];
    }

    f32x4 acc[4][4];
    #pragma unroll
    for (int fr = 0; fr < 4; ++fr)
      #pragma unroll
      for (int fc = 0; fc < 4; ++fc) acc[fr][fc] = (f32x4){0.f, 0.f, 0.f, 0.f};

    // x double-buffer: [c&1] is compile-time under full unroll (static idx)
    bf16x8 xh[2][4], xl[2][4];
    #pragma unroll
    for (int fc = 0; fc < 4; ++fc) {
      xh[0][fc] = *reinterpret_cast<const bf16x8*>(xp[fc]);
      xl[0][fc] = *reinterpret_cast<const bf16x8*>(xp[fc] + 512);
    }

    #pragma unroll
    for (int c = 0; c < 8; ++c) {
      const int cur = c & 1;
      if (c < 7) {
        #pragma unroll
        for (int fc = 0; fc < 4; ++fc) {
          xh[cur ^ 1][fc] = *reinterpret_cast<const bf16x8*>(xp[fc] + (c + 1) * 64);
          xl[cur ^ 1][fc] = *reinterpret_cast<const bf16x8*>(xp[fc] + (c + 1) * 64 + 512);
        }
      }
      const char* LB = lds + c * 16384;
      bf16x8 ch[4], cl[4];
      #pragma unroll
      for (int fr = 0; fr < 4; ++fr)
        ch[fr] = *reinterpret_cast<const bf16x8*>(LB + aOff[fr] + koX);
      #pragma unroll
      for (int fr = 0; fr < 4; ++fr)
        cl[fr] = *reinterpret_cast<const bf16x8*>(LB + 8192 + aOff[fr] + koX);

      MM16(ch, xh[cur]);          // c_hi x x_hi
      MM16(cl, xh[cur]);          // c_lo x x_hi
      MM16(ch, xl[cur]);          // c_hi x x_lo
    }

    // ---- epilogue: dist -> u64 key -> fold over lg -> atomicMin ----
    // C layout: row(code) = wr*64 + fr*16 + lg*4 + rg ; col(x) = wc*64 + fc*16 + l15
    u64t bk[4] = {~0ull, ~0ull, ~0ull, ~0ull};
    #pragma unroll
    for (int fr = 0; fr < 4; ++fr) {
      const int cbase = cb * 128 + wr * 64 + fr * 16 + lg * 4;
      float4 en4 = *reinterpret_cast<const float4*>(enorm + cbase);
      const float en[4] = {en4.x, en4.y, en4.z, en4.w};
      #pragma unroll
      for (int fc = 0; fc < 4; ++fc)
        #pragma unroll
        for (int rg = 0; rg < 4; ++rg) {
          const float dist = (fcol[fc] + en[rg]) - 2.0f * acc[fr][fc][rg];
          const u64t key = ((u64t)__builtin_bit_cast(u32t, dist) << 32) | (u32t)(cbase + rg);
          if (key < bk[fc]) bk[fc] = key;
        }
    }
    #pragma unroll
    for (int off = 16; off <= 32; off <<= 1)
      #pragma unroll
      for (int fc = 0; fc < 4; ++fc) {
        const u64t o = shfl_xor_u64(bk[fc], off);
        if (o < bk[fc]) bk[fc] = o;
      }
    if (lg == 0) {
      #pragma unroll
      for (int fc = 0; fc < 4; ++fc)
        atomicMin(&keyArr[nb * 256 + wc * 64 + fc * 16 + l15], bk[fc]);
    }
  }
#undef MM16
}

// --- gather: key -> code -> out write + loss partial ---
__global__ __launch_bounds__(256) void vq_gather(const u64t* __restrict__ keyArr,
                                                 const float* __restrict__ Etg,
                                                 const float* __restrict__ x,
                                                 float* __restrict__ out,
                                                 float* __restrict__ partial) {
  __shared__ int codes[128];
  __shared__ float lpart[4];
  const int t  = threadIdx.x;
  const int r0 = blockIdx.x * 128;
  if (t < 128) codes[t] = (int)(u32t)keyArr[r0 + t];
  __syncthreads();
  float lsum = 0.f;
  for (int rr = 0; rr < 128; ++rr) {
    const int row  = r0 + rr;
    const int code = codes[rr];
    const float q  = Etg[(size_t)code * DDIM + t];
    const float xv = x[(size_t)row * DDIM + t];
    out[(size_t)row * DDIM + t] = q;
    const float df = q - xv;
    lsum += df * df;
  }
  #pragma unroll
  for (int off = 32; off; off >>= 1) lsum += __shfl_xor(lsum, off);
  if ((t & 63) == 0) lpart[t >> 6] = lsum;
  __syncthreads();
  if (t == 0) partial[blockIdx.x] = (lpart[0] + lpart[1]) + (lpart[2] + lpart[3]);
}

// --- final deterministic loss reduction ---
__global__ __launch_bounds__(256) void vq_final(const float* __restrict__ partial,
                                                float* __restrict__ loss_out) {
  double s = 0.0;
  for (int i = threadIdx.x; i < 512; i += 256) s += (double)partial[i];
  #pragma unroll
  for (int off = 32; off; off >>= 1) s += __shfl_xor(s, off);
  __shared__ double sh[4];
  if ((threadIdx.x & 63) == 0) sh[threadIdx.x >> 6] = s;
  __syncthreads();
  if (threadIdx.x == 0) {
    const double mean = (sh[0] + sh[1] + sh[2] + sh[3]) / 16777216.0;
    loss_out[0] = (float)(0.25 * mean - mean);
  }
}

extern "C" void kernel_launch(void* const* d_in, const int* in_sizes, int n_in,
                              void* d_out, int out_size, void* d_ws, size_t ws_size,
                              hipStream_t stream) {
  const float* x = (const float*)d_in[0];   // [65536, 256]
  const float* E = (const float*)d_in[1];   // [256, 2048]
  float* out = (float*)d_out;
  char*  ws  = (char*)d_ws;

  // ws layout (bytes): keyArr 512K | enorm 8K | frow 256K | partial 2K | Etg 2M | Bp 2M (~4.8 MB)
  u64t*  keyArr  = (u64t*)ws;
  float* enorm   = (float*)(ws + 524288);
  float* frow    = (float*)(ws + 524288 + 8192);
  float* partial = (float*)(ws + 524288 + 8192 + 262144);
  float* Etg     = (float*)(ws + 524288 + 8192 + 262144 + 2048);
  unsigned short* Bp = (unsigned short*)(ws + 524288 + 8192 + 262144 + 2048 + 2097152);

  unsigned short* Ap = (unsigned short*)d_out;   // A' overlay on out (consumed before gather writes)

  hipFuncSetAttribute(reinterpret_cast<const void*>(vq_nn),
                      hipFuncAttributeMaxDynamicSharedMemorySize, 131072);

  prep_A  <<<NROWS / 8, 256, 0, stream>>>(x, Ap, frow, keyArr);
  prep_B  <<<KCODE,     256, 0, stream>>>(E, Bp, enorm, Etg);
  vq_nn   <<<256,       512, 131072, stream>>>(Ap, Bp, enorm, frow, keyArr);
  vq_gather<<<512,      256, 0, stream>>>(keyArr, Etg, x, out, partial);
  vq_final<<<1,         256, 0, stream>>>(partial, out + (size_t)NROWS * DDIM);
}

// Round 13
// 283.200 us; speedup vs baseline: 1.0484x; 1.0484x over previous
//
#include <hip/hip_runtime.h>

typedef __attribute__((ext_vector_type(8))) short bf16x8;
typedef __attribute__((ext_vector_type(16))) float f32x16;
typedef __attribute__((ext_vector_type(8))) unsigned short u16x8;
typedef unsigned long long u64t;
typedef unsigned int u32t;

#define NROWS 65536
#define DDIM  256
#define KCODE 2048

__device__ __forceinline__ unsigned short f2bf_rne(float f) {
  unsigned int u = __builtin_bit_cast(unsigned int, f);
  unsigned int r = (u + 0x7fffu + ((u >> 16) & 1u)) >> 16;
  return (unsigned short)r;
}
__device__ __forceinline__ float bf2f(unsigned short h) {
  unsigned int u = ((unsigned int)h) << 16;
  return __builtin_bit_cast(float, u);
}

typedef const unsigned int __attribute__((address_space(1)))* gp1_t;
typedef unsigned int __attribute__((address_space(3)))* lp3_t;
__device__ __forceinline__ void gload_lds16(const void* g, void* l) {
  __builtin_amdgcn_global_load_lds((gp1_t)g, (lp3_t)l, 16, 0, 0);
}

__device__ __forceinline__ u64t shfl_xor_u64(u64t v, int off) {
  u32t lo = (u32t)v, hi = (u32t)(v >> 32);
  lo = __shfl_xor(lo, off);
  hi = __shfl_xor(hi, off);
  return ((u64t)hi << 32) | lo;
}

// --- prep A: x -> [hi(256)|lo(256)] bf16 per row (overlay on d_out) + ||x||^2 + key init ---
__global__ __launch_bounds__(256) void prep_A(const float* __restrict__ x,
                                              unsigned short* __restrict__ Ap,
                                              float* __restrict__ frow,
                                              u64t* __restrict__ keyArr) {
  const int t   = threadIdx.x;
  const int row = blockIdx.x * 8 + (t >> 5);
  const int d0  = (t & 31) * 8;
  const float* xr = x + (size_t)row * DDIM + d0;
  float4 v0 = *reinterpret_cast<const float4*>(xr);
  float4 v1 = *reinterpret_cast<const float4*>(xr + 4);
  float vv[8] = {v0.x, v0.y, v0.z, v0.w, v1.x, v1.y, v1.z, v1.w};
  u16x8 hi, lo;
  float ss = 0.f;
  #pragma unroll
  for (int i = 0; i < 8; ++i) {
    ss += vv[i] * vv[i];
    unsigned short h = f2bf_rne(vv[i]);
    hi[i] = h;
    lo[i] = f2bf_rne(vv[i] - bf2f(h));
  }
  char* rowp = (char*)Ap + (size_t)row * 1024;
  *reinterpret_cast<u16x8*>(rowp + d0 * 2)       = hi;
  *reinterpret_cast<u16x8*>(rowp + 512 + d0 * 2) = lo;
  #pragma unroll
  for (int off = 16; off; off >>= 1) ss += __shfl_xor(ss, off);
  if ((t & 31) == 0) { frow[row] = ss; keyArr[row] = ~0ull; }
}

// --- prep B: E[d][k] -> Bp[k][512]=[hi(256)|lo(256)] bf16 k-major; enorm; Etg[k][d] fp32 ---
__global__ __launch_bounds__(256) void prep_B(const float* __restrict__ E,
                                              unsigned short* __restrict__ Bp,
                                              float* __restrict__ enorm,
                                              float* __restrict__ Etg) {
  const int k0 = blockIdx.x;
  const int d  = threadIdx.x;
  float v = E[(size_t)d * KCODE + k0];
  Etg[(size_t)k0 * DDIM + d] = v;
  unsigned short h = f2bf_rne(v);
  unsigned short l = f2bf_rne(v - bf2f(h));
  unsigned short* col = Bp + (size_t)k0 * 512;
  col[d] = h; col[256 + d] = l;
  float s = v * v;
  #pragma unroll
  for (int off = 32; off; off >>= 1) s += __shfl_xor(s, off);
  __shared__ float wsum[4];
  if ((threadIdx.x & 63) == 0) wsum[threadIdx.x >> 6] = s;
  __syncthreads();
  if (threadIdx.x == 0) enorm[k0] = (wsum[0] + wsum[1]) + (wsum[2] + wsum[3]);
}

// --- main: r9's proven schedule (2-barrier chunk + vmcnt(12)) with 32x32x16
// MFMA fragments: half the MFMA instructions, 1/3 fewer LDS reads, +15% pipe
// ceiling. Tile 256 codes x 256 x per block; wave = 128 codes x 64 x =
// 4x2 fragments of 32x32; acc[4][2] f32x16. Codes in LDS (dbuf 64KB),
// x per-lane in named double-buffered registers.
__global__ __launch_bounds__(512, 2) void vq_nn(
    const unsigned short* __restrict__ Ap,   // x packed  [row][hi|lo] 1024 B/row
    const unsigned short* __restrict__ Bp,   // codes     [k][hi|lo]   1024 B/code
    const float* __restrict__ enorm,
    const float* __restrict__ frow,
    u64t* __restrict__ keyArr)
{
  extern __shared__ __align__(16) char lds[];   // 2 x { ch 16K | cl 16K } = 64 KB

  const int tid = threadIdx.x;
  const int w   = tid >> 6;
  const int l   = tid & 63;
  const int l31 = l & 31;
  const int lh  = l >> 5;          // k-group 0/1 within fragment
  const int wr  = w >> 2;          // code half (0..1): 128 codes
  const int wc  = w & 3;           // x quarter (0..3): 64 cols

  // XCD-aware swizzle (FETCH 371->106MB, r7)
  const int xcd = blockIdx.x & 7;
  const int seq = blockIdx.x >> 3;
  const int cb  = seq & 7;                  // code block 0..7 (256 codes)
  const int nb  = xcd * 32 + (seq >> 3);    // x-row block 0..255 (256 rows)

  const int rl0  = tid >> 2;                // 0..127 staging row
  const int c16  = (tid & 3) * 16;
  const int srcS = c16 ^ (((rl0 >> 1) & 3) << 4);   // pre-swizzled source (involution)
  const char* BpB = (const char*)Bp + (size_t)cb * 256 * 1024;
  const char* ApB = (const char*)Ap + (size_t)nb * 256 * 1024;

  // fcol + per-lane x row pointers (B-fragment: col = l&31, k-group = l>>5)
  float fcol[2];
  const char* xp[2];
  #pragma unroll
  for (int cf = 0; cf < 2; ++cf) {
    const int col = wc * 64 + cf * 32 + l31;
    fcol[cf] = frow[nb * 256 + col];
    xp[cf]   = ApB + (size_t)col * 1024 + lh * 16;
  }

  // stage codes chunk cc: ch 16KB @+0, cl 16KB @+16384 (4 gloads)
  auto STC = [&](int cc, char* buf) {
    #pragma unroll
    for (int rnd = 0; rnd < 2; ++rnd) {
      const size_t ro = (size_t)(rnd * 128 + rl0) * 1024 + (size_t)cc * 64 + srcS;
      gload_lds16(BpB + ro,       buf + rnd * 8192 + w * 1024);
      gload_lds16(BpB + ro + 512, buf + 16384 + rnd * 8192 + w * 1024);
    }
  };

  const int swz = ((l31 >> 1) & 3) << 4;    // matches fill involution
  int aOff[4];
  #pragma unroll
  for (int fr = 0; fr < 4; ++fr) aOff[fr] = (wr * 128 + fr * 32 + l31) * 64;

  f32x16 acc[4][2];
  #pragma unroll
  for (int fr = 0; fr < 4; ++fr)
    #pragma unroll
    for (int cf = 0; cf < 2; ++cf)
      #pragma unroll
      for (int q = 0; q < 16; ++q) acc[fr][cf][q] = 0.f;

// load x chunk cc into a named register set: [ks][cf], hi and lo
#define LDX(cc, XH, XL)                                                       \
  _Pragma("unroll")                                                           \
  for (int ks_ = 0; ks_ < 2; ++ks_)                                           \
    _Pragma("unroll")                                                         \
    for (int cf_ = 0; cf_ < 2; ++cf_) {                                       \
      XH[ks_][cf_] = *(const bf16x8*)(xp[cf_] + (cc) * 64 + ks_ * 32);        \
      XL[ks_][cf_] = *(const bf16x8*)(xp[cf_] + (cc) * 64 + ks_ * 32 + 512);  \
    }

// one k=16 step: read A frags, 24 MFMA (ch*xh, cl*xh, ch*xl)
#define KSTEP(CURB, ks, XH, XL)                                               \
  {                                                                           \
    const int ko_ = ((ks) * 32 + lh * 16) ^ swz;                              \
    bf16x8 ch_[4], cl_[4];                                                    \
    _Pragma("unroll")                                                         \
    for (int fr_ = 0; fr_ < 4; ++fr_)                                         \
      ch_[fr_] = *(const bf16x8*)((CURB) + aOff[fr_] + ko_);                  \
    __builtin_amdgcn_s_setprio(1);                                            \
    _Pragma("unroll")                                                         \
    for (int fr_ = 0; fr_ < 4; ++fr_) {                                       \
      acc[fr_][0] = __builtin_amdgcn_mfma_f32_32x32x16_bf16(ch_[fr_], XH[ks][0], acc[fr_][0], 0, 0, 0); \
      acc[fr_][1] = __builtin_amdgcn_mfma_f32_32x32x16_bf16(ch_[fr_], XH[ks][1], acc[fr_][1], 0, 0, 0); \
    }                                                                         \
    __builtin_amdgcn_s_setprio(0);                                            \
    _Pragma("unroll")                                                         \
    for (int fr_ = 0; fr_ < 4; ++fr_)                                         \
      cl_[fr_] = *(const bf16x8*)((CURB) + 16384 + aOff[fr_] + ko_);          \
    __builtin_amdgcn_s_setprio(1);                                            \
    _Pragma("unroll")                                                         \
    for (int fr_ = 0; fr_ < 4; ++fr_) {                                       \
      acc[fr_][0] = __builtin_amdgcn_mfma_f32_32x32x16_bf16(cl_[fr_], XH[ks][0], acc[fr_][0], 0, 0, 0); \
      acc[fr_][1] = __builtin_amdgcn_mfma_f32_32x32x16_bf16(cl_[fr_], XH[ks][1], acc[fr_][1], 0, 0, 0); \
    }                                                                         \
    _Pragma("unroll")                                                         \
    for (int fr_ = 0; fr_ < 4; ++fr_) {                                       \
      acc[fr_][0] = __builtin_amdgcn_mfma_f32_32x32x16_bf16(ch_[fr_], XL[ks][0], acc[fr_][0], 0, 0, 0); \
      acc[fr_][1] = __builtin_amdgcn_mfma_f32_32x32x16_bf16(ch_[fr_], XL[ks][1], acc[fr_][1], 0, 0, 0); \
    }                                                                         \
    __builtin_amdgcn_s_setprio(0);                                            \
  }

// one chunk: prefetch batch {4 stage + 8 x-loads} -> vmcnt(12) publishes c
#define CHUNK(c, CURB, NXTB, XHc, XLc, XHn, XLn, PREF)                        \
  if (PREF) {                                                                 \
    STC((c) + 1, NXTB);                                                       \
    LDX((c) + 1, XHn, XLn);                                                   \
    asm volatile("s_waitcnt vmcnt(12)" ::: "memory");                         \
  } else {                                                                    \
    asm volatile("s_waitcnt vmcnt(0)" ::: "memory");                          \
  }                                                                           \
  __builtin_amdgcn_s_barrier();                                               \
  KSTEP(CURB, 0, XHc, XLc)                                                    \
  KSTEP(CURB, 1, XHc, XLc)                                                    \
  asm volatile("s_waitcnt lgkmcnt(0)" ::: "memory");                          \
  __builtin_amdgcn_sched_barrier(0);                                          \
  __builtin_amdgcn_s_barrier();

  char* b0 = lds;
  char* b1 = lds + 32768;
  bf16x8 xhA[2][2], xlA[2][2], xhB[2][2], xlB[2][2];

  // prologue: chunk 0 -> b0 + x(0) -> set A
  STC(0, b0);
  LDX(0, xhA, xlA);
  asm volatile("s_waitcnt vmcnt(0)" ::: "memory");
  __builtin_amdgcn_s_barrier();

  for (int cp = 0; cp < 4; ++cp) {
    const int c0 = cp * 2;
    CHUNK(c0,     b0, b1, xhA, xlA, xhB, xlB, true)
    CHUNK(c0 + 1, b1, b0, xhB, xlB, xhA, xlA, (cp < 3))
  }
#undef CHUNK
#undef KSTEP
#undef LDX

  // ---- epilogue: dist -> packed u64 key -> fold -> atomicMin per x-col ----
  // C layout (32x32, m74/m101): col(x) = l&31, row(code) = (reg&3) + 8*(reg>>2) + 4*(l>>5)
  u64t bk[2] = {~0ull, ~0ull};
  #pragma unroll
  for (int fr = 0; fr < 4; ++fr) {
    const int cb0 = cb * 256 + wr * 128 + fr * 32 + 4 * lh;
    #pragma unroll
    for (int g2 = 0; g2 < 4; ++g2) {
      float4 en4 = *reinterpret_cast<const float4*>(enorm + cb0 + g2 * 8);
      const float en[4] = {en4.x, en4.y, en4.z, en4.w};
      #pragma unroll
      for (int r = 0; r < 4; ++r) {
        const int reg  = g2 * 4 + r;
        const int code = cb0 + g2 * 8 + r;
        #pragma unroll
        for (int cf = 0; cf < 2; ++cf) {
          const float dist = (fcol[cf] + en[r]) - 2.0f * acc[fr][cf][reg];
          const u64t key = ((u64t)__builtin_bit_cast(u32t, dist) << 32) | (u32t)code;
          if (key < bk[cf]) bk[cf] = key;
        }
      }
    }
  }
  #pragma unroll
  for (int cf = 0; cf < 2; ++cf) {
    const u64t o = shfl_xor_u64(bk[cf], 32);
    if (o < bk[cf]) bk[cf] = o;
  }
  if (lh == 0) {
    #pragma unroll
    for (int cf = 0; cf < 2; ++cf)
      atomicMin(&keyArr[nb * 256 + wc * 64 + cf * 32 + l31], bk[cf]);
  }
}

// --- gather: key -> code -> out write + loss partial ---
__global__ __launch_bounds__(256) void vq_gather(const u64t* __restrict__ keyArr,
                                                 const float* __restrict__ Etg,
                                                 const float* __restrict__ x,
                                                 float* __restrict__ out,
                                                 float* __restrict__ partial) {
  __shared__ int codes[128];
  __shared__ float lpart[4];
  const int t  = threadIdx.x;
  const int r0 = blockIdx.x * 128;
  if (t < 128) codes[t] = (int)(u32t)keyArr[r0 + t];
  __syncthreads();
  float lsum = 0.f;
  for (int rr = 0; rr < 128; ++rr) {
    const int row  = r0 + rr;
    const int code = codes[rr];
    const float q  = Etg[(size_t)code * DDIM + t];
    const float xv = x[(size_t)row * DDIM + t];
    out[(size_t)row * DDIM + t] = q;
    const float df = q - xv;
    lsum += df * df;
  }
  #pragma unroll
  for (int off = 32; off; off >>= 1) lsum += __shfl_xor(lsum, off);
  if ((t & 63) == 0) lpart[t >> 6] = lsum;
  __syncthreads();
  if (t == 0) partial[blockIdx.x] = (lpart[0] + lpart[1]) + (lpart[2] + lpart[3]);
}

// --- final deterministic loss reduction ---
__global__ __launch_bounds__(256) void vq_final(const float* __restrict__ partial,
                                                float* __restrict__ loss_out) {
  double s = 0.0;
  for (int i = threadIdx.x; i < 512; i += 256) s += (double)partial[i];
  #pragma unroll
  for (int off = 32; off; off >>= 1) s += __shfl_xor(s, off);
  __shared__ double sh[4];
  if ((threadIdx.x & 63) == 0) sh[threadIdx.x >> 6] = s;
  __syncthreads();
  if (threadIdx.x == 0) {
    const double mean = (sh[0] + sh[1] + sh[2] + sh[3]) / 16777216.0;
    loss_out[0] = (float)(0.25 * mean - mean);
  }
}

extern "C" void kernel_launch(void* const* d_in, const int* in_sizes, int n_in,
                              void* d_out, int out_size, void* d_ws, size_t ws_size,
                              hipStream_t stream) {
  const float* x = (const float*)d_in[0];   // [65536, 256]
  const float* E = (const float*)d_in[1];   // [256, 2048]
  float* out = (float*)d_out;
  char*  ws  = (char*)d_ws;

  // ws layout (bytes): keyArr 512K | enorm 8K | frow 256K | partial 2K | Etg 2M | Bp 2M (~4.8 MB)
  u64t*  keyArr  = (u64t*)ws;
  float* enorm   = (float*)(ws + 524288);
  float* frow    = (float*)(ws + 524288 + 8192);
  float* partial = (float*)(ws + 524288 + 8192 + 262144);
  float* Etg     = (float*)(ws + 524288 + 8192 + 262144 + 2048);
  unsigned short* Bp = (unsigned short*)(ws + 524288 + 8192 + 262144 + 2048 + 2097152);

  unsigned short* Ap = (unsigned short*)d_out;   // A' overlay on out (consumed before gather writes)

  hipFuncSetAttribute(reinterpret_cast<const void*>(vq_nn),
                      hipFuncAttributeMaxDynamicSharedMemorySize, 65536);

  prep_A  <<<NROWS / 8, 256, 0, stream>>>(x, Ap, frow, keyArr);
  prep_B  <<<KCODE,     256, 0, stream>>>(E, Bp, enorm, Etg);
  vq_nn   <<<2048,      512, 65536, stream>>>(Ap, Bp, enorm, frow, keyArr);
  vq_gather<<<512,      256, 0, stream>>>(keyArr, Etg, x, out, partial);
  vq_final<<<1,         256, 0, stream>>>(partial, out + (size_t)NROWS * DDIM);
}

// Round 14
// 277.487 us; speedup vs baseline: 1.0700x; 1.0206x over previous
//
#include <hip/hip_runtime.h>

typedef __attribute__((ext_vector_type(8))) short bf16x8;
typedef __attribute__((ext_vector_type(16))) float f32x16;
typedef __attribute__((ext_vector_type(8))) unsigned short u16x8;
typedef unsigned long long u64t;
typedef unsigned int u32t;

#define NROWS 65536
#define DDIM  256
#define KCODE 2048

__device__ __forceinline__ unsigned short f2bf_rne(float f) {
  unsigned int u = __builtin_bit_cast(unsigned int, f);
  unsigned int r = (u + 0x7fffu + ((u >> 16) & 1u)) >> 16;
  return (unsigned short)r;
}
__device__ __forceinline__ float bf2f(unsigned short h) {
  unsigned int u = ((unsigned int)h) << 16;
  return __builtin_bit_cast(float, u);
}

typedef const unsigned int __attribute__((address_space(1)))* gp1_t;
typedef unsigned int __attribute__((address_space(3)))* lp3_t;
__device__ __forceinline__ void gload_lds16(const void* g, void* l) {
  __builtin_amdgcn_global_load_lds((gp1_t)g, (lp3_t)l, 16, 0, 0);
}

__device__ __forceinline__ u64t shfl_xor_u64(u64t v, int off) {
  u32t lo = (u32t)v, hi = (u32t)(v >> 32);
  lo = __shfl_xor(lo, off);
  hi = __shfl_xor(hi, off);
  return ((u64t)hi << 32) | lo;
}

// --- prep A: x -> [hi(256)|lo(256)] bf16 per row (overlay on d_out) + ||x||^2 + key init ---
__global__ __launch_bounds__(256) void prep_A(const float* __restrict__ x,
                                              unsigned short* __restrict__ Ap,
                                              float* __restrict__ frow,
                                              u64t* __restrict__ keyArr) {
  const int t   = threadIdx.x;
  const int row = blockIdx.x * 8 + (t >> 5);
  const int d0  = (t & 31) * 8;
  const float* xr = x + (size_t)row * DDIM + d0;
  float4 v0 = *reinterpret_cast<const float4*>(xr);
  float4 v1 = *reinterpret_cast<const float4*>(xr + 4);
  float vv[8] = {v0.x, v0.y, v0.z, v0.w, v1.x, v1.y, v1.z, v1.w};
  u16x8 hi, lo;
  float ss = 0.f;
  #pragma unroll
  for (int i = 0; i < 8; ++i) {
    ss += vv[i] * vv[i];
    unsigned short h = f2bf_rne(vv[i]);
    hi[i] = h;
    lo[i] = f2bf_rne(vv[i] - bf2f(h));
  }
  char* rowp = (char*)Ap + (size_t)row * 1024;
  *reinterpret_cast<u16x8*>(rowp + d0 * 2)       = hi;
  *reinterpret_cast<u16x8*>(rowp + 512 + d0 * 2) = lo;
  #pragma unroll
  for (int off = 16; off; off >>= 1) ss += __shfl_xor(ss, off);
  if ((t & 31) == 0) { frow[row] = ss; keyArr[row] = ~0ull; }
}

// --- prep B: E -> Bp in FRAGMENT-MAJOR layout + enorm + Etg ---
// Per (cb, chunk c): 32KB block = [hi 16K | lo 16K], each 16K =
// [frag_g:8][ks:2][lane:64] x 16B, where for code k0: row=k0&255,
// frag_g=row>>5, lane = lh*32 + (row&31); dim d: c=d>>5, kin=d&31,
// ks=kin>>4, lh=(kin>>3)&1, j=kin&7. LDS staging is then a flat linear
// copy and every MFMA A-fragment read is base + lane*16 (conflict-free).
__global__ __launch_bounds__(256) void prep_B(const float* __restrict__ E,
                                              unsigned short* __restrict__ Bp,
                                              float* __restrict__ enorm,
                                              float* __restrict__ Etg) {
  const int k0 = blockIdx.x;
  const int d  = threadIdx.x;
  float v = E[(size_t)d * KCODE + k0];
  Etg[(size_t)k0 * DDIM + d] = v;
  unsigned short h = f2bf_rne(v);
  unsigned short l = f2bf_rne(v - bf2f(h));

  const int cbk = k0 >> 8;
  const int row = k0 & 255;
  const int c   = d >> 5;
  const int kin = d & 31;
  const int ks  = kin >> 4;
  const int lh  = (kin >> 3) & 1;
  const int j   = kin & 7;
  const size_t base = (size_t)cbk * 262144 + (size_t)c * 32768;
  const size_t off  = (size_t)(row >> 5) * 2048 + ks * 1024 + lh * 512
                    + (row & 31) * 16 + j * 2;
  *reinterpret_cast<unsigned short*>((char*)Bp + base + off)         = h;
  *reinterpret_cast<unsigned short*>((char*)Bp + base + 16384 + off) = l;

  float s = v * v;
  #pragma unroll
  for (int off2 = 32; off2; off2 >>= 1) s += __shfl_xor(s, off2);
  __shared__ float wsum[4];
  if ((threadIdx.x & 63) == 0) wsum[threadIdx.x >> 6] = s;
  __syncthreads();
  if (threadIdx.x == 0) enorm[k0] = (wsum[0] + wsum[1]) + (wsum[2] + wsum[3]);
}

// --- main: r9 schedule (2-barrier chunk + vmcnt(12)) with 32x32x16 MFMA and
// fragment-major LDS (no swizzle; all fragment reads are base + lane*16,
// guaranteed conflict-free). Tile 256 codes x 256 x; wave = 128 codes x 64 x
// = 4x2 fragments; acc[4][2] f32x16. Codes in LDS (dbuf 64KB), x in regs.
__global__ __launch_bounds__(512, 2) void vq_nn(
    const unsigned short* __restrict__ Ap,   // x packed  [row][hi|lo] 1024 B/row
    const unsigned short* __restrict__ Bp,   // codes fragment-major, 256KB/cb
    const float* __restrict__ enorm,
    const float* __restrict__ frow,
    u64t* __restrict__ keyArr)
{
  extern __shared__ __align__(16) char lds[];   // 2 x 32KB = 64 KB

  const int tid = threadIdx.x;
  const int w   = tid >> 6;
  const int l   = tid & 63;
  const int l31 = l & 31;
  const int lh  = l >> 5;          // k-group 0/1 within fragment
  const int wr  = w >> 2;          // code half (0..1): 128 codes
  const int wc  = w & 3;           // x quarter (0..3): 64 cols

  // XCD-aware swizzle (FETCH 371->106MB, r7)
  const int xcd = blockIdx.x & 7;
  const int seq = blockIdx.x >> 3;
  const int cb  = seq & 7;                  // code block 0..7 (256 codes)
  const int nb  = xcd * 32 + (seq >> 3);    // x-row block 0..255 (256 rows)

  const char* BpB = (const char*)Bp + (size_t)cb * 262144;
  const char* ApB = (const char*)Ap + (size_t)nb * 256 * 1024;

  // fcol + per-lane x row pointers (B-fragment: col = l&31, k-group = l>>5)
  float fcol[2];
  const char* xp[2];
  #pragma unroll
  for (int cf = 0; cf < 2; ++cf) {
    const int col = wc * 64 + cf * 32 + l31;
    fcol[cf] = frow[nb * 256 + col];
    xp[cf]   = ApB + (size_t)col * 1024 + lh * 16;
  }

  // stage codes chunk cc: flat linear 32KB copy (4 x 8KB gloads)
  auto STC = [&](int cc, char* buf) {
    const char* src = BpB + (size_t)cc * 32768;
    #pragma unroll
    for (int rnd = 0; rnd < 4; ++rnd)
      gload_lds16(src + rnd * 8192 + tid * 16, buf + rnd * 8192 + w * 1024);
  };

  const int lofs = l * 16;         // lane-contiguous fragment read offset
  int aOff[4];
  #pragma unroll
  for (int fr = 0; fr < 4; ++fr) aOff[fr] = (wr * 4 + fr) * 2048;

  f32x16 acc[4][2];
  #pragma unroll
  for (int fr = 0; fr < 4; ++fr)
    #pragma unroll
    for (int cf = 0; cf < 2; ++cf)
      #pragma unroll
      for (int q = 0; q < 16; ++q) acc[fr][cf][q] = 0.f;

// load x chunk cc into a named register set: [ks][cf], hi and lo
#define LDX(cc, XH, XL)                                                       \
  _Pragma("unroll")                                                           \
  for (int ks_ = 0; ks_ < 2; ++ks_)                                           \
    _Pragma("unroll")                                                         \
    for (int cf_ = 0; cf_ < 2; ++cf_) {                                       \
      XH[ks_][cf_] = *(const bf16x8*)(xp[cf_] + (cc) * 64 + ks_ * 32);        \
      XL[ks_][cf_] = *(const bf16x8*)(xp[cf_] + (cc) * 64 + ks_ * 32 + 512);  \
    }

// one k=16 step: read A frags (linear), 24 MFMA (ch*xh, cl*xh, ch*xl)
#define KSTEP(CURB, ks, XH, XL)                                               \
  {                                                                           \
    bf16x8 ch_[4], cl_[4];                                                    \
    _Pragma("unroll")                                                         \
    for (int fr_ = 0; fr_ < 4; ++fr_)                                         \
      ch_[fr_] = *(const bf16x8*)((CURB) + aOff[fr_] + (ks) * 1024 + lofs);   \
    __builtin_amdgcn_s_setprio(1);                                            \
    _Pragma("unroll")                                                         \
    for (int fr_ = 0; fr_ < 4; ++fr_) {                                       \
      acc[fr_][0] = __builtin_amdgcn_mfma_f32_32x32x16_bf16(ch_[fr_], XH[ks][0], acc[fr_][0], 0, 0, 0); \
      acc[fr_][1] = __builtin_amdgcn_mfma_f32_32x32x16_bf16(ch_[fr_], XH[ks][1], acc[fr_][1], 0, 0, 0); \
    }                                                                         \
    __builtin_amdgcn_s_setprio(0);                                            \
    _Pragma("unroll")                                                         \
    for (int fr_ = 0; fr_ < 4; ++fr_)                                         \
      cl_[fr_] = *(const bf16x8*)((CURB) + 16384 + aOff[fr_] + (ks) * 1024 + lofs); \
    __builtin_amdgcn_s_setprio(1);                                            \
    _Pragma("unroll")                                                         \
    for (int fr_ = 0; fr_ < 4; ++fr_) {                                       \
      acc[fr_][0] = __builtin_amdgcn_mfma_f32_32x32x16_bf16(cl_[fr_], XH[ks][0], acc[fr_][0], 0, 0, 0); \
      acc[fr_][1] = __builtin_amdgcn_mfma_f32_32x32x16_bf16(cl_[fr_], XH[ks][1], acc[fr_][1], 0, 0, 0); \
    }                                                                         \
    _Pragma("unroll")                                                         \
    for (int fr_ = 0; fr_ < 4; ++fr_) {                                       \
      acc[fr_][0] = __builtin_amdgcn_mfma_f32_32x32x16_bf16(ch_[fr_], XL[ks][0], acc[fr_][0], 0, 0, 0); \
      acc[fr_][1] = __builtin_amdgcn_mfma_f32_32x32x16_bf16(ch_[fr_], XL[ks][1], acc[fr_][1], 0, 0, 0); \
    }                                                                         \
    __builtin_amdgcn_s_setprio(0);                                            \
  }

// one chunk: prefetch batch {4 stage + 8 x-loads} -> vmcnt(12) publishes c
#define CHUNK(c, CURB, NXTB, XHc, XLc, XHn, XLn, PREF)                        \
  if (PREF) {                                                                 \
    STC((c) + 1, NXTB);                                                       \
    LDX((c) + 1, XHn, XLn);                                                   \
    asm volatile("s_waitcnt vmcnt(12)" ::: "memory");                         \
  } else {                                                                    \
    asm volatile("s_waitcnt vmcnt(0)" ::: "memory");                          \
  }                                                                           \
  __builtin_amdgcn_s_barrier();                                               \
  KSTEP(CURB, 0, XHc, XLc)                                                    \
  KSTEP(CURB, 1, XHc, XLc)                                                    \
  asm volatile("s_waitcnt lgkmcnt(0)" ::: "memory");                          \
  __builtin_amdgcn_sched_barrier(0);                                          \
  __builtin_amdgcn_s_barrier();

  char* b0 = lds;
  char* b1 = lds + 32768;
  bf16x8 xhA[2][2], xlA[2][2], xhB[2][2], xlB[2][2];

  // prologue: chunk 0 -> b0 + x(0) -> set A
  STC(0, b0);
  LDX(0, xhA, xlA);
  asm volatile("s_waitcnt vmcnt(0)" ::: "memory");
  __builtin_amdgcn_s_barrier();

  for (int cp = 0; cp < 4; ++cp) {
    const int c0 = cp * 2;
    CHUNK(c0,     b0, b1, xhA, xlA, xhB, xlB, true)
    CHUNK(c0 + 1, b1, b0, xhB, xlB, xhA, xlA, (cp < 3))
  }
#undef CHUNK
#undef KSTEP
#undef LDX

  // ---- epilogue: dist -> packed u64 key -> fold -> atomicMin per x-col ----
  // C layout (32x32, m74/m101): col(x) = l&31, row(code) = (reg&3) + 8*(reg>>2) + 4*(l>>5)
  u64t bk[2] = {~0ull, ~0ull};
  #pragma unroll
  for (int fr = 0; fr < 4; ++fr) {
    const int cb0 = cb * 256 + wr * 128 + fr * 32 + 4 * lh;
    #pragma unroll
    for (int g2 = 0; g2 < 4; ++g2) {
      float4 en4 = *reinterpret_cast<const float4*>(enorm + cb0 + g2 * 8);
      const float en[4] = {en4.x, en4.y, en4.z, en4.w};
      #pragma unroll
      for (int r = 0; r < 4; ++r) {
        const int reg  = g2 * 4 + r;
        const int code = cb0 + g2 * 8 + r;
        #pragma unroll
        for (int cf = 0; cf < 2; ++cf) {
          const float dist = (fcol[cf] + en[r]) - 2.0f * acc[fr][cf][reg];
          const u64t key = ((u64t)__builtin_bit_cast(u32t, dist) << 32) | (u32t)code;
          if (key < bk[cf]) bk[cf] = key;
        }
      }
    }
  }
  #pragma unroll
  for (int cf = 0; cf < 2; ++cf) {
    const u64t o = shfl_xor_u64(bk[cf], 32);
    if (o < bk[cf]) bk[cf] = o;
  }
  if (lh == 0) {
    #pragma unroll
    for (int cf = 0; cf < 2; ++cf)
      atomicMin(&keyArr[nb * 256 + wc * 64 + cf * 32 + l31], bk[cf]);
  }
}

// --- gather: key -> code -> out write + loss partial ---
__global__ __launch_bounds__(256) void vq_gather(const u64t* __restrict__ keyArr,
                                                 const float* __restrict__ Etg,
                                                 const float* __restrict__ x,
                                                 float* __restrict__ out,
                                                 float* __restrict__ partial) {
  __shared__ int codes[128];
  __shared__ float lpart[4];
  const int t  = threadIdx.x;
  const int r0 = blockIdx.x * 128;
  if (t < 128) codes[t] = (int)(u32t)keyArr[r0 + t];
  __syncthreads();
  float lsum = 0.f;
  for (int rr = 0; rr < 128; ++rr) {
    const int row  = r0 + rr;
    const int code = codes[rr];
    const float q  = Etg[(size_t)code * DDIM + t];
    const float xv = x[(size_t)row * DDIM + t];
    out[(size_t)row * DDIM + t] = q;
    const float df = q - xv;
    lsum += df * df;
  }
  #pragma unroll
  for (int off = 32; off; off >>= 1) lsum += __shfl_xor(lsum, off);
  if ((t & 63) == 0) lpart[t >> 6] = lsum;
  __syncthreads();
  if (t == 0) partial[blockIdx.x] = (lpart[0] + lpart[1]) + (lpart[2] + lpart[3]);
}

// --- final deterministic loss reduction ---
__global__ __launch_bounds__(256) void vq_final(const float* __restrict__ partial,
                                                float* __restrict__ loss_out) {
  double s = 0.0;
  for (int i = threadIdx.x; i < 512; i += 256) s += (double)partial[i];
  #pragma unroll
  for (int off = 32; off; off >>= 1) s += __shfl_xor(s, off);
  __shared__ double sh[4];
  if ((threadIdx.x & 63) == 0) sh[threadIdx.x >> 6] = s;
  __syncthreads();
  if (threadIdx.x == 0) {
    const double mean = (sh[0] + sh[1] + sh[2] + sh[3]) / 16777216.0;
    loss_out[0] = (float)(0.25 * mean - mean);
  }
}

extern "C" void kernel_launch(void* const* d_in, const int* in_sizes, int n_in,
                              void* d_out, int out_size, void* d_ws, size_t ws_size,
                              hipStream_t stream) {
  const float* x = (const float*)d_in[0];   // [65536, 256]
  const float* E = (const float*)d_in[1];   // [256, 2048]
  float* out = (float*)d_out;
  char*  ws  = (char*)d_ws;

  // ws layout (bytes): keyArr 512K | enorm 8K | frow 256K | partial 2K | Etg 2M | Bp 2M (~4.8 MB)
  u64t*  keyArr  = (u64t*)ws;
  float* enorm   = (float*)(ws + 524288);
  float* frow    = (float*)(ws + 524288 + 8192);
  float* partial = (float*)(ws + 524288 + 8192 + 262144);
  float* Etg     = (float*)(ws + 524288 + 8192 + 262144 + 2048);
  unsigned short* Bp = (unsigned short*)(ws + 524288 + 8192 + 262144 + 2048 + 2097152);

  unsigned short* Ap = (unsigned short*)d_out;   // A' overlay on out (consumed before gather writes)

  hipFuncSetAttribute(reinterpret_cast<const void*>(vq_nn),
                      hipFuncAttributeMaxDynamicSharedMemorySize, 65536);

  prep_A  <<<NROWS / 8, 256, 0, stream>>>(x, Ap, frow, keyArr);
  prep_B  <<<KCODE,     256, 0, stream>>>(E, Bp, enorm, Etg);
  vq_nn   <<<2048,      512, 65536, stream>>>(Ap, Bp, enorm, frow, keyArr);
  vq_gather<<<512,      256, 0, stream>>>(keyArr, Etg, x, out, partial);
  vq_final<<<1,         256, 0, stream>>>(partial, out + (size_t)NROWS * DDIM);
}

// Round 15
// 277.468 us; speedup vs baseline: 1.0701x; 1.0001x over previous
//
#include <hip/hip_runtime.h>

typedef __attribute__((ext_vector_type(8))) short bf16x8;
typedef __attribute__((ext_vector_type(16))) float f32x16;
typedef __attribute__((ext_vector_type(8))) unsigned short u16x8;
typedef unsigned long long u64t;
typedef unsigned int u32t;

#define NROWS 65536
#define DDIM  256
#define KCODE 2048

__device__ __forceinline__ unsigned short f2bf_rne(float f) {
  unsigned int u = __builtin_bit_cast(unsigned int, f);
  unsigned int r = (u + 0x7fffu + ((u >> 16) & 1u)) >> 16;
  return (unsigned short)r;
}
__device__ __forceinline__ float bf2f(unsigned short h) {
  unsigned int u = ((unsigned int)h) << 16;
  return __builtin_bit_cast(float, u);
}

typedef const unsigned int __attribute__((address_space(1)))* gp1_t;
typedef unsigned int __attribute__((address_space(3)))* lp3_t;
__device__ __forceinline__ void gload_lds16(const void* g, void* l) {
  __builtin_amdgcn_global_load_lds((gp1_t)g, (lp3_t)l, 16, 0, 0);
}

__device__ __forceinline__ u64t shfl_xor_u64(u64t v, int off) {
  u32t lo = (u32t)v, hi = (u32t)(v >> 32);
  lo = __shfl_xor(lo, off);
  hi = __shfl_xor(hi, off);
  return ((u64t)hi << 32) | lo;
}

// --- prep A: x -> [hi(256)|lo(256)] bf16 per row (overlay on d_out) + ||x||^2 + key init ---
__global__ __launch_bounds__(256) void prep_A(const float* __restrict__ x,
                                              unsigned short* __restrict__ Ap,
                                              float* __restrict__ frow,
                                              u64t* __restrict__ keyArr) {
  const int t   = threadIdx.x;
  const int row = blockIdx.x * 8 + (t >> 5);
  const int d0  = (t & 31) * 8;
  const float* xr = x + (size_t)row * DDIM + d0;
  float4 v0 = *reinterpret_cast<const float4*>(xr);
  float4 v1 = *reinterpret_cast<const float4*>(xr + 4);
  float vv[8] = {v0.x, v0.y, v0.z, v0.w, v1.x, v1.y, v1.z, v1.w};
  u16x8 hi, lo;
  float ss = 0.f;
  #pragma unroll
  for (int i = 0; i < 8; ++i) {
    ss += vv[i] * vv[i];
    unsigned short h = f2bf_rne(vv[i]);
    hi[i] = h;
    lo[i] = f2bf_rne(vv[i] - bf2f(h));
  }
  char* rowp = (char*)Ap + (size_t)row * 1024;
  *reinterpret_cast<u16x8*>(rowp + d0 * 2)       = hi;
  *reinterpret_cast<u16x8*>(rowp + 512 + d0 * 2) = lo;
  #pragma unroll
  for (int off = 16; off; off >>= 1) ss += __shfl_xor(ss, off);
  if ((t & 31) == 0) { frow[row] = ss; keyArr[row] = ~0ull; }
}

// --- prep B: E -> Bp in FRAGMENT-MAJOR layout + enorm + Etg ---
// Per (cb, chunk c): 32KB block = [hi 16K | lo 16K], each 16K =
// [frag_g:8][ks:2][lane:64] x 16B, where for code k0: row=k0&255,
// frag_g=row>>5, lane = lh*32 + (row&31); dim d: c=d>>5, kin=d&31,
// ks=kin>>4, lh=(kin>>3)&1, j=kin&7. LDS staging is then a flat linear
// copy and every MFMA A-fragment read is base + lane*16 (conflict-free).
__global__ __launch_bounds__(256) void prep_B(const float* __restrict__ E,
                                              unsigned short* __restrict__ Bp,
                                              float* __restrict__ enorm,
                                              float* __restrict__ Etg) {
  const int k0 = blockIdx.x;
  const int d  = threadIdx.x;
  float v = E[(size_t)d * KCODE + k0];
  Etg[(size_t)k0 * DDIM + d] = v;
  unsigned short h = f2bf_rne(v);
  unsigned short l = f2bf_rne(v - bf2f(h));

  const int cbk = k0 >> 8;
  const int row = k0 & 255;
  const int c   = d >> 5;
  const int kin = d & 31;
  const int ks  = kin >> 4;
  const int lh  = (kin >> 3) & 1;
  const int j   = kin & 7;
  const size_t base = (size_t)cbk * 262144 + (size_t)c * 32768;
  const size_t off  = (size_t)(row >> 5) * 2048 + ks * 1024 + lh * 512
                    + (row & 31) * 16 + j * 2;
  *reinterpret_cast<unsigned short*>((char*)Bp + base + off)         = h;
  *reinterpret_cast<unsigned short*>((char*)Bp + base + 16384 + off) = l;

  float s = v * v;
  #pragma unroll
  for (int off2 = 32; off2; off2 >>= 1) s += __shfl_xor(s, off2);
  __shared__ float wsum[4];
  if ((threadIdx.x & 63) == 0) wsum[threadIdx.x >> 6] = s;
  __syncthreads();
  if (threadIdx.x == 0) enorm[k0] = (wsum[0] + wsum[1]) + (wsum[2] + wsum[3]);
}

// --- main: r9 schedule (2-barrier chunk + vmcnt(12)) with 32x32x16 MFMA and
// fragment-major LDS (no swizzle; all fragment reads are base + lane*16,
// guaranteed conflict-free). Tile 256 codes x 256 x; wave = 128 codes x 64 x
// = 4x2 fragments; acc[4][2] f32x16. Codes in LDS (dbuf 64KB), x in regs.
__global__ __launch_bounds__(512, 2) void vq_nn(
    const unsigned short* __restrict__ Ap,   // x packed  [row][hi|lo] 1024 B/row
    const unsigned short* __restrict__ Bp,   // codes fragment-major, 256KB/cb
    const float* __restrict__ enorm,
    const float* __restrict__ frow,
    u64t* __restrict__ keyArr)
{
  extern __shared__ __align__(16) char lds[];   // 2 x 32KB = 64 KB

  const int tid = threadIdx.x;
  const int w   = tid >> 6;
  const int l   = tid & 63;
  const int l31 = l & 31;
  const int lh  = l >> 5;          // k-group 0/1 within fragment
  const int wr  = w >> 2;          // code half (0..1): 128 codes
  const int wc  = w & 3;           // x quarter (0..3): 64 cols

  // XCD-aware swizzle (FETCH 371->106MB, r7)
  const int xcd = blockIdx.x & 7;
  const int seq = blockIdx.x >> 3;
  const int cb  = seq & 7;                  // code block 0..7 (256 codes)
  const int nb  = xcd * 32 + (seq >> 3);    // x-row block 0..255 (256 rows)

  const char* BpB = (const char*)Bp + (size_t)cb * 262144;
  const char* ApB = (const char*)Ap + (size_t)nb * 256 * 1024;

  // fcol + per-lane x row pointers (B-fragment: col = l&31, k-group = l>>5)
  float fcol[2];
  const char* xp[2];
  #pragma unroll
  for (int cf = 0; cf < 2; ++cf) {
    const int col = wc * 64 + cf * 32 + l31;
    fcol[cf] = frow[nb * 256 + col];
    xp[cf]   = ApB + (size_t)col * 1024 + lh * 16;
  }

  // stage codes chunk cc: flat linear 32KB copy (4 x 8KB gloads)
  auto STC = [&](int cc, char* buf) {
    const char* src = BpB + (size_t)cc * 32768;
    #pragma unroll
    for (int rnd = 0; rnd < 4; ++rnd)
      gload_lds16(src + rnd * 8192 + tid * 16, buf + rnd * 8192 + w * 1024);
  };

  const int lofs = l * 16;         // lane-contiguous fragment read offset
  int aOff[4];
  #pragma unroll
  for (int fr = 0; fr < 4; ++fr) aOff[fr] = (wr * 4 + fr) * 2048;

  f32x16 acc[4][2];
  #pragma unroll
  for (int fr = 0; fr < 4; ++fr)
    #pragma unroll
    for (int cf = 0; cf < 2; ++cf)
      #pragma unroll
      for (int q = 0; q < 16; ++q) acc[fr][cf][q] = 0.f;

// load x chunk cc into a named register set: [ks][cf], hi and lo
#define LDX(cc, XH, XL)                                                       \
  _Pragma("unroll")                                                           \
  for (int ks_ = 0; ks_ < 2; ++ks_)                                           \
    _Pragma("unroll")                                                         \
    for (int cf_ = 0; cf_ < 2; ++cf_) {                                       \
      XH[ks_][cf_] = *(const bf16x8*)(xp[cf_] + (cc) * 64 + ks_ * 32);        \
      XL[ks_][cf_] = *(const bf16x8*)(xp[cf_] + (cc) * 64 + ks_ * 32 + 512);  \
    }

// one k=16 step: read A frags (linear), 24 MFMA (ch*xh, cl*xh, ch*xl)
#define KSTEP(CURB, ks, XH, XL)                                               \
  {                                                                           \
    bf16x8 ch_[4], cl_[4];                                                    \
    _Pragma("unroll")                                                         \
    for (int fr_ = 0; fr_ < 4; ++fr_)                                         \
      ch_[fr_] = *(const bf16x8*)((CURB) + aOff[fr_] + (ks) * 1024 + lofs);   \
    __builtin_amdgcn_s_setprio(1);                                            \
    _Pragma("unroll")                                                         \
    for (int fr_ = 0; fr_ < 4; ++fr_) {                                       \
      acc[fr_][0] = __builtin_amdgcn_mfma_f32_32x32x16_bf16(ch_[fr_], XH[ks][0], acc[fr_][0], 0, 0, 0); \
      acc[fr_][1] = __builtin_amdgcn_mfma_f32_32x32x16_bf16(ch_[fr_], XH[ks][1], acc[fr_][1], 0, 0, 0); \
    }                                                                         \
    __builtin_amdgcn_s_setprio(0);                                            \
    _Pragma("unroll")                                                         \
    for (int fr_ = 0; fr_ < 4; ++fr_)                                         \
      cl_[fr_] = *(const bf16x8*)((CURB) + 16384 + aOff[fr_] + (ks) * 1024 + lofs); \
    __builtin_amdgcn_s_setprio(1);                                            \
    _Pragma("unroll")                                                         \
    for (int fr_ = 0; fr_ < 4; ++fr_) {                                       \
      acc[fr_][0] = __builtin_amdgcn_mfma_f32_32x32x16_bf16(cl_[fr_], XH[ks][0], acc[fr_][0], 0, 0, 0); \
      acc[fr_][1] = __builtin_amdgcn_mfma_f32_32x32x16_bf16(cl_[fr_], XH[ks][1], acc[fr_][1], 0, 0, 0); \
    }                                                                         \
    _Pragma("unroll")                                                         \
    for (int fr_ = 0; fr_ < 4; ++fr_) {                                       \
      acc[fr_][0] = __builtin_amdgcn_mfma_f32_32x32x16_bf16(ch_[fr_], XL[ks][0], acc[fr_][0], 0, 0, 0); \
      acc[fr_][1] = __builtin_amdgcn_mfma_f32_32x32x16_bf16(ch_[fr_], XL[ks][1], acc[fr_][1], 0, 0, 0); \
    }                                                                         \
    __builtin_amdgcn_s_setprio(0);                                            \
  }

// one chunk: prefetch batch {4 stage + 8 x-loads} -> vmcnt(12) publishes c
#define CHUNK(c, CURB, NXTB, XHc, XLc, XHn, XLn, PREF)                        \
  if (PREF) {                                                                 \
    STC((c) + 1, NXTB);                                                       \
    LDX((c) + 1, XHn, XLn);                                                   \
    asm volatile("s_waitcnt vmcnt(12)" ::: "memory");                         \
  } else {                                                                    \
    asm volatile("s_waitcnt vmcnt(0)" ::: "memory");                          \
  }                                                                           \
  __builtin_amdgcn_s_barrier();                                               \
  KSTEP(CURB, 0, XHc, XLc)                                                    \
  KSTEP(CURB, 1, XHc, XLc)                                                    \
  asm volatile("s_waitcnt lgkmcnt(0)" ::: "memory");                          \
  __builtin_amdgcn_sched_barrier(0);                                          \
  __builtin_amdgcn_s_barrier();

  char* b0 = lds;
  char* b1 = lds + 32768;
  bf16x8 xhA[2][2], xlA[2][2], xhB[2][2], xlB[2][2];

  // prologue: chunk 0 -> b0 + x(0) -> set A
  STC(0, b0);
  LDX(0, xhA, xlA);
  asm volatile("s_waitcnt vmcnt(0)" ::: "memory");
  __builtin_amdgcn_s_barrier();

  for (int cp = 0; cp < 4; ++cp) {
    const int c0 = cp * 2;
    CHUNK(c0,     b0, b1, xhA, xlA, xhB, xlB, true)
    CHUNK(c0 + 1, b1, b0, xhB, xlB, xhA, xlA, (cp < 3))
  }
#undef CHUNK
#undef KSTEP
#undef LDX

  // ---- epilogue: dist -> packed u64 key -> fold -> atomicMin per x-col ----
  // C layout (32x32, m74/m101): col(x) = l&31, row(code) = (reg&3) + 8*(reg>>2) + 4*(l>>5)
  u64t bk[2] = {~0ull, ~0ull};
  #pragma unroll
  for (int fr = 0; fr < 4; ++fr) {
    const int cb0 = cb * 256 + wr * 128 + fr * 32 + 4 * lh;
    #pragma unroll
    for (int g2 = 0; g2 < 4; ++g2) {
      float4 en4 = *reinterpret_cast<const float4*>(enorm + cb0 + g2 * 8);
      const float en[4] = {en4.x, en4.y, en4.z, en4.w};
      #pragma unroll
      for (int r = 0; r < 4; ++r) {
        const int reg  = g2 * 4 + r;
        const int code = cb0 + g2 * 8 + r;
        #pragma unroll
        for (int cf = 0; cf < 2; ++cf) {
          const float dist = (fcol[cf] + en[r]) - 2.0f * acc[fr][cf][reg];
          const u64t key = ((u64t)__builtin_bit_cast(u32t, dist) << 32) | (u32t)code;
          if (key < bk[cf]) bk[cf] = key;
        }
      }
    }
  }
  #pragma unroll
  for (int cf = 0; cf < 2; ++cf) {
    const u64t o = shfl_xor_u64(bk[cf], 32);
    if (o < bk[cf]) bk[cf] = o;
  }
  if (lh == 0) {
    #pragma unroll
    for (int cf = 0; cf < 2; ++cf)
      atomicMin(&keyArr[nb * 256 + wc * 64 + cf * 32 + l31], bk[cf]);
  }
}

// --- gather: key -> code -> out write + loss partial ---
__global__ __launch_bounds__(256) void vq_gather(const u64t* __restrict__ keyArr,
                                                 const float* __restrict__ Etg,
                                                 const float* __restrict__ x,
                                                 float* __restrict__ out,
                                                 float* __restrict__ partial) {
  __shared__ int codes[128];
  __shared__ float lpart[4];
  const int t  = threadIdx.x;
  const int r0 = blockIdx.x * 128;
  if (t < 128) codes[t] = (int)(u32t)keyArr[r0 + t];
  __syncthreads();
  float lsum = 0.f;
  for (int rr = 0; rr < 128; ++rr) {
    const int row  = r0 + rr;
    const int code = codes[rr];
    const float q  = Etg[(size_t)code * DDIM + t];
    const float xv = x[(size_t)row * DDIM + t];
    out[(size_t)row * DDIM + t] = q;
    const float df = q - xv;
    lsum += df * df;
  }
  #pragma unroll
  for (int off = 32; off; off >>= 1) lsum += __shfl_xor(lsum, off);
  if ((t & 63) == 0) lpart[t >> 6] = lsum;
  __syncthreads();
  if (t == 0) partial[blockIdx.x] = (lpart[0] + lpart[1]) + (lpart[2] + lpart[3]);
}

// --- final deterministic loss reduction ---
__global__ __launch_bounds__(256) void vq_final(const float* __restrict__ partial,
                                                float* __restrict__ loss_out) {
  double s = 0.0;
  for (int i = threadIdx.x; i < 512; i += 256) s += (double)partial[i];
  #pragma unroll
  for (int off = 32; off; off >>= 1) s += __shfl_xor(s, off);
  __shared__ double sh[4];
  if ((threadIdx.x & 63) == 0) sh[threadIdx.x >> 6] = s;
  __syncthreads();
  if (threadIdx.x == 0) {
    const double mean = (sh[0] + sh[1] + sh[2] + sh[3]) / 16777216.0;
    loss_out[0] = (float)(0.25 * mean - mean);
  }
}

extern "C" void kernel_launch(void* const* d_in, const int* in_sizes, int n_in,
                              void* d_out, int out_size, void* d_ws, size_t ws_size,
                              hipStream_t stream) {
  const float* x = (const float*)d_in[0];   // [65536, 256]
  const float* E = (const float*)d_in[1];   // [256, 2048]
  float* out = (float*)d_out;
  char*  ws  = (char*)d_ws;

  // ws layout (bytes): keyArr 512K | enorm 8K | frow 256K | partial 2K | Etg 2M | Bp 2M (~4.8 MB)
  u64t*  keyArr  = (u64t*)ws;
  float* enorm   = (float*)(ws + 524288);
  float* frow    = (float*)(ws + 524288 + 8192);
  float* partial = (float*)(ws + 524288 + 8192 + 262144);
  float* Etg     = (float*)(ws + 524288 + 8192 + 262144 + 2048);
  unsigned short* Bp = (unsigned short*)(ws + 524288 + 8192 + 262144 + 2048 + 2097152);

  unsigned short* Ap = (unsigned short*)d_out;   // A' overlay on out (consumed before gather writes)

  hipFuncSetAttribute(reinterpret_cast<const void*>(vq_nn),
                      hipFuncAttributeMaxDynamicSharedMemorySize, 65536);

  prep_A  <<<NROWS / 8, 256, 0, stream>>>(x, Ap, frow, keyArr);
  prep_B  <<<KCODE,     256, 0, stream>>>(E, Bp, enorm, Etg);
  vq_nn   <<<2048,      512, 65536, stream>>>(Ap, Bp, enorm, frow, keyArr);
  vq_gather<<<512,      256, 0, stream>>>(keyArr, Etg, x, out, partial);
  vq_final<<<1,         256, 0, stream>>>(partial, out + (size_t)NROWS * DDIM);
}